// Round 8
// baseline (2414.081 us; speedup 1.0000x reference)
//
#include <hip/hip_runtime.h>
#include <hip/hip_bf16.h>
#include <hip/hip_cooperative_groups.h>

namespace cg = cooperative_groups;

#define GN 50000
#define GE 600000
#define DD 128
#define TQ 4096          // RBF table quantization (4097 rows per layer)
#define NBOND 2268       // 12*27*7 bond combo rows
#define TROWS (2*(TQ+1) + NBOND)   // table-build blocks per layer
#define SCB 49           // scan blocks of 1024 -> 49*1024 = 50176 >= GN+1
#define NBANK 16         // stats banks
#define SSET (NBANK*256) // floats per stats set: [bank][0..127 sum | 128..255 sumsq]
#define NB 782           // (GN+63)/64 row tiles; coop grid (4 blocks/CU cap = 1024 >= 782)
#define LDK 136          // LDS bf16 A-tile stride: 128+8 shorts -> 2-way only (free, m136)

typedef __attribute__((ext_vector_type(8))) short short8;
typedef __attribute__((ext_vector_type(4))) unsigned short ushort4v;
typedef __attribute__((ext_vector_type(4))) float floatx4;

__device__ __forceinline__ unsigned short f2b(float f) {
    __hip_bfloat16 h = __float2bfloat16(f);
    return __builtin_bit_cast(unsigned short, h);
}
__device__ __forceinline__ float b2f_lo(unsigned int u) { return __uint_as_float(u << 16); }
__device__ __forceinline__ float b2f_hi(unsigned int u) { return __uint_as_float(u & 0xffff0000u); }
__device__ __forceinline__ float bs2f(short s) {
    return __uint_as_float(((unsigned int)(unsigned short)s) << 16);
}

// ---------------------------------------------------------------- atom encoder -> h (bf16)
__global__ __launch_bounds__(256) void atom_kernel(
    const int* __restrict__ x, const int* __restrict__ atom_off,
    const float* __restrict__ atom_emb, unsigned short* __restrict__ h)
{
    int t = blockIdx.x * 256 + threadIdx.x;
    if (t >= GN * DD) return;
    int n = t >> 7, d = t & 127;
    float s = 0.f;
#pragma unroll
    for (int f = 0; f < 9; f++) {
        int idx = x[n * 9 + f] + atom_off[f];
        s += atom_emb[idx * DD + d];
    }
    h[t] = f2b(s);
}

// ---------------------------------------------------------------- CSR build
__global__ __launch_bounds__(256) void hist_kernel(const int* __restrict__ ei, int* __restrict__ count)
{
    int e = blockIdx.x * 256 + threadIdx.x;
    if (e < GE) atomicAdd(&count[ei[GE + e]], 1);
}

__global__ __launch_bounds__(1024) void scan1_kernel(
    const int* __restrict__ count, int* __restrict__ row_start, int* __restrict__ blocksum)
{
    __shared__ int sh[1024];
    int t = threadIdx.x;
    int idx = blockIdx.x * 1024 + t;
    int v = (idx < GN) ? count[idx] : 0;
    sh[t] = v;
    __syncthreads();
    for (int off = 1; off < 1024; off <<= 1) {
        int u = (t >= off) ? sh[t - off] : 0;
        __syncthreads();
        sh[t] += u;
        __syncthreads();
    }
    if (idx <= GN) row_start[idx] = (t == 0) ? 0 : sh[t - 1];   // local exclusive
    if (t == 1023) blocksum[blockIdx.x] = sh[1023];
}

__global__ __launch_bounds__(64) void scan2_kernel(
    const int* __restrict__ blocksum, int* __restrict__ blockoff)
{
    int t = threadIdx.x;
    int v = (t < SCB) ? blocksum[t] : 0;
#pragma unroll
    for (int off = 1; off < 64; off <<= 1) {
        int u = __shfl_up(v, off);
        if (t >= off) v += u;
    }
    int e = __shfl_up(v, 1);
    if (t == 0) e = 0;
    if (t < SCB) blockoff[t] = e;
}

__global__ __launch_bounds__(1024) void scan3_kernel(
    int* __restrict__ row_start, const int* __restrict__ blockoff)
{
    int idx = blockIdx.x * 1024 + threadIdx.x;
    if (idx <= GN) row_start[idx] += blockoff[blockIdx.x];
}

// scatter + pack per-edge metadata {src, q1|q2<<16, bondcombo, 0} in CSR order
__global__ __launch_bounds__(256) void scatter_kernel(
    const int* __restrict__ ei, const int* __restrict__ eai, const float* __restrict__ eaf,
    const int* __restrict__ row_start, int* __restrict__ fill, int4* __restrict__ ep)
{
    int e = blockIdx.x * 256 + threadIdx.x;
    if (e < GE) {
        int d = ei[GE + e];
        int p = row_start[d] + atomicAdd(&fill[d], 1);
        int src = ei[e];
        float x1 = eaf[2 * e], x2 = eaf[2 * e + 1];
        int q1 = (int)(x1 * (float)TQ + 0.5f); q1 = min(max(q1, 0), TQ);
        int q2 = (int)(x2 * (float)TQ + 0.5f); q2 = min(max(q2, 0), TQ);
        int b0 = eai[3 * e], b1 = eai[3 * e + 1], b2 = eai[3 * e + 2];
        ep[p] = make_int4(src, q1 | (q2 << 16), (b0 * 27 + b1) * 7 + b2, 0);
    }
}

// ---------------------------------------------------------------- tables for ALL layers (bf16)
__global__ __launch_bounds__(128) void tables_kernel(
    const float* __restrict__ W_bl, const float* __restrict__ b_bl,
    const float* __restrict__ W_pr, const float* __restrict__ b_pr,
    const float* __restrict__ bond_emb, const int* __restrict__ bond_off,
    unsigned short* __restrict__ tbl_bl, unsigned short* __restrict__ tbl_pr,
    unsigned short* __restrict__ tbl_bond)
{
    int l = blockIdx.x / TROWS;
    int b = blockIdx.x % TROWS;
    int d = threadIdx.x;
    const float* W_bl_l = W_bl + (size_t)l * 20 * DD;
    const float* W_pr_l = W_pr + (size_t)l * 20 * DD;
    const float* bemb_l = bond_emb + (size_t)l * 46 * DD;
    if (b < (TQ + 1)) {
        float xq = b * (1.0f / TQ);
        float s = b_bl[(size_t)l * DD + d] + b_pr[(size_t)l * DD + d];
#pragma unroll
        for (int k = 0; k < 20; k++) {
            float dl = xq - 0.1f * k;
            s += __expf(-10.f * dl * dl) * W_bl_l[k * DD + d];
        }
        tbl_bl[((size_t)l * (TQ + 1) + b) * DD + d] = f2b(s);
    } else if (b < 2 * (TQ + 1)) {
        int q = b - (TQ + 1);
        float xq = q * (1.0f / TQ);
        float s = 0.f;
#pragma unroll
        for (int k = 0; k < 20; k++) {
            float dl = xq - 0.05f * k;
            s += __expf(-dl * dl) * W_pr_l[k * DD + d];
        }
        tbl_pr[((size_t)l * (TQ + 1) + q) * DD + d] = f2b(s);
    } else {
        int r = b - 2 * (TQ + 1);
        int b0 = r / 189;            // 27*7
        int rem = r % 189;
        int b1 = rem / 7, b2 = rem % 7;
        tbl_bond[((size_t)l * NBOND + r) * DD + d] =
            f2b(bemb_l[(b0 + bond_off[0]) * DD + d]
              + bemb_l[(b1 + bond_off[1]) * DD + d]
              + bemb_l[(b2 + bond_off[2]) * DD + d]);
    }
}

// ---------------------------------------------------------------- W -> MFMA B-fragment hi/lo packs
__global__ __launch_bounds__(256) void wfrag_kernel(
    const float* __restrict__ W1, const float* __restrict__ W2,
    unsigned short* __restrict__ wf_hi, unsigned short* __restrict__ wf_lo)
{
    int t = blockIdx.x * 256 + threadIdx.x;    // 0..20479
    if (t >= 10 * 2048) return;
    int mat = t >> 11;
    int rem = t & 2047;
    int kt = rem >> 9;
    int rem2 = rem & 511;
    int nt = rem2 >> 6;
    int lane = rem2 & 63;
    const float* src = (mat & 1) ? (W2 + (size_t)(mat >> 1) * DD * DD)
                                 : (W1 + (size_t)(mat >> 1) * DD * DD);
    int n = nt * 16 + (lane & 15);
    int k0 = kt * 32 + (lane >> 4) * 8;
    size_t base = (size_t)mat * 16384 + (size_t)((kt * 8 + nt) * 64 + lane) * 8;
#pragma unroll
    for (int j = 0; j < 8; j++) {
        float w = src[(size_t)(k0 + j) * DD + n];
        unsigned short hi = f2b(w);
        wf_hi[base + j] = hi;
        wf_lo[base + j] = f2b(w - bs2f((short)hi));
    }
}

// ================================================================ FUSED per-layer kernel
// Cooperative: one launch replaces edge + gemm0 + gemm1 (+ bn_apply on layer 4).
// Phase 1: edge aggregate (R3 ping-pong structure, grid-stride over nodes) -> A (f32)
// Phase 2: stage A->LDS hi/lo; K-loop W1 -> acc1 IN REGISTERS (z1 never hits HBM); stats1
// Phase 3: grid.sync; reduce stats1 -> bn1; write relu(bn1(z1)) hi/lo back to LDS
// Phase 4: K-loop W2 -> acc2; z2_bf + stats2 (LAST: extra grid.sync, bn2, write out)
// Geometry: 782 blocks x 256thr, LDS 35.8KB + launch_bounds(256,4) -> 4 blocks/CU
// -> co-resident capacity 1024 >= 782 (coop launch API validates; no deadlock path).
template <int L0, int LAST>
__global__ __launch_bounds__(256, 4) void layer_kernel(
    const int4* __restrict__ ep,
    const unsigned short* __restrict__ tbl_bl, const unsigned short* __restrict__ tbl_pr,
    const unsigned short* __restrict__ tbl_bond,
    const unsigned short* __restrict__ hsrc, const int* __restrict__ row_start,
    const float* __restrict__ eps_gin, int layer,
    const float* __restrict__ stats_prev, const float* __restrict__ g_prev,
    const float* __restrict__ b_prev,
    float* __restrict__ A,
    const unsigned short* __restrict__ wf1_hi, const unsigned short* __restrict__ wf1_lo,
    const unsigned short* __restrict__ wf2_hi, const unsigned short* __restrict__ wf2_lo,
    const float* __restrict__ bias1, const float* __restrict__ bias2,
    float* __restrict__ stats1, float* __restrict__ stats2,
    const float* __restrict__ bn1_g, const float* __restrict__ bn1_b,
    const float* __restrict__ bn2_g, const float* __restrict__ bn2_b,
    unsigned short* __restrict__ z2bf, float* __restrict__ out)
{
    __shared__ unsigned short Ahi[64 * LDK];   // 17 KB
    __shared__ unsigned short Alo[64 * LDK];   // 17 KB
    __shared__ float sc_s[DD], tr_s[DD];
    cg::grid_group grid = cg::this_grid();
    int tid = threadIdx.x, wid = tid >> 6, lane = tid & 63;

    // ---- phase 0: bn coefs of PREVIOUS layer's bn2 (for hsrc) ----
    if (!L0) {
        if (tid < DD) {
            float s = 0.f, q = 0.f;
#pragma unroll
            for (int bk = 0; bk < NBANK; bk++) {
                s += stats_prev[bk * 256 + tid];
                q += stats_prev[bk * 256 + 128 + tid];
            }
            float m = s * (1.0f / GN);
            float v = q * (1.0f / GN) - m * m;
            float sc = g_prev[tid] * rsqrtf(v + 1e-5f);
            sc_s[tid] = sc;
            tr_s[tid] = b_prev[tid] - m * sc;
        }
        __syncthreads();
    }
    float sc0 = 1.f, tr0 = 0.f, sc1 = 1.f, tr1 = 0.f;
    if (!L0) {
        sc0 = sc_s[2 * lane];     tr0 = tr_s[2 * lane];
        sc1 = sc_s[2 * lane + 1]; tr1 = tr_s[2 * lane + 1];
    }

    // ---- phase 1: edge aggregate, grid-stride wave-per-node (R3 structure) ----
    {
        const unsigned int* hu = (const unsigned int*)hsrc;
        const unsigned int* tb = (const unsigned int*)tbl_bl;
        const unsigned int* tp = (const unsigned int*)tbl_pr;
        const unsigned int* tg = (const unsigned int*)tbl_bond;
        float eps1 = 1.f + eps_gin[layer];
        int gw = blockIdx.x * 4 + wid;

        for (int n = gw; n < GN; n += NB * 4) {
            int s0 = __builtin_amdgcn_readfirstlane(row_start[n]);
            int s1 = __builtin_amdgcn_readfirstlane(row_start[n + 1]);
            float a0 = 0.f, a1 = 0.f;

            auto meta = [&](int pb, int4 (&mm)[4]) {
#pragma unroll
                for (int j = 0; j < 4; j++) mm[j] = ep[pb + j];   // uniform -> s_load
            };
            auto issue = [&](const int4 (&mm)[4], unsigned int (&ub)[4], unsigned int (&up)[4],
                             unsigned int (&ug)[4], unsigned int (&uh)[4]) {
#pragma unroll
                for (int j = 0; j < 4; j++) {
                    ub[j] = tb[(size_t)(mm[j].y & 0xffff) * 64 + lane];
                    up[j] = tp[(size_t)((unsigned)mm[j].y >> 16) * 64 + lane];
                    ug[j] = tg[(size_t)mm[j].z * 64 + lane];
                    uh[j] = hu[(size_t)mm[j].x * 64 + lane];
                }
            };
            auto consume = [&](const unsigned int (&ub)[4], const unsigned int (&up)[4],
                               const unsigned int (&ug)[4], const unsigned int (&uh)[4]) {
#pragma unroll
                for (int j = 0; j < 4; j++) {
                    float h0, h1;
                    if (!L0) {
                        h0 = fmaxf(fmaf(b2f_lo(uh[j]), sc0, tr0), 0.f);
                        h1 = fmaxf(fmaf(b2f_hi(uh[j]), sc1, tr1), 0.f);
                    } else {
                        h0 = b2f_lo(uh[j]);
                        h1 = b2f_hi(uh[j]);
                    }
                    a0 += fmaxf(h0 + b2f_lo(ub[j]) + b2f_lo(up[j]) + b2f_lo(ug[j]), 0.f);
                    a1 += fmaxf(h1 + b2f_hi(ub[j]) + b2f_hi(up[j]) + b2f_hi(ug[j]), 0.f);
                }
            };

            int nfull = (s1 - s0) >> 2;
            {
                int4 mA[4], mB[4];
                unsigned int ubA[4], upA[4], ugA[4], uhA[4];
                unsigned int ubB[4], upB[4], ugB[4], uhB[4];
                if (nfull > 0) {
                    meta(s0, mA);
                    issue(mA, ubA, upA, ugA, uhA);
                    int i = 1;
                    for (; i + 1 < nfull; i += 2) {
                        meta(s0 + i * 4, mB);
                        meta(s0 + (i + 1) * 4, mA);
                        issue(mB, ubB, upB, ugB, uhB);
                        consume(ubA, upA, ugA, uhA);
                        issue(mA, ubA, upA, ugA, uhA);
                        consume(ubB, upB, ugB, uhB);
                    }
                    if (i < nfull) {
                        meta(s0 + i * 4, mB);
                        issue(mB, ubB, upB, ugB, uhB);
                        consume(ubA, upA, ugA, uhA);
                        consume(ubB, upB, ugB, uhB);
                    } else {
                        consume(ubA, upA, ugA, uhA);
                    }
                }
            }
            for (int p = s0 + nfull * 4; p < s1; p++) {   // tail < 4 edges
                int4 m0 = ep[p];
                unsigned int ub0 = tb[(size_t)(m0.y & 0xffff) * 64 + lane];
                unsigned int up0 = tp[(size_t)((unsigned)m0.y >> 16) * 64 + lane];
                unsigned int ug0 = tg[(size_t)m0.z * 64 + lane];
                unsigned int uh0 = hu[(size_t)m0.x * 64 + lane];
                float h00, h01;
                if (!L0) {
                    h00 = fmaxf(fmaf(b2f_lo(uh0), sc0, tr0), 0.f);
                    h01 = fmaxf(fmaf(b2f_hi(uh0), sc1, tr1), 0.f);
                } else {
                    h00 = b2f_lo(uh0);
                    h01 = b2f_hi(uh0);
                }
                a0 += fmaxf(h00 + b2f_lo(ub0) + b2f_lo(up0) + b2f_lo(ug0), 0.f);
                a1 += fmaxf(h01 + b2f_hi(ub0) + b2f_hi(up0) + b2f_hi(ug0), 0.f);
            }

            unsigned int un = hu[(size_t)n * 64 + lane];
            float n0, n1;
            if (!L0) {
                n0 = fmaxf(fmaf(b2f_lo(un), sc0, tr0), 0.f);
                n1 = fmaxf(fmaf(b2f_hi(un), sc1, tr1), 0.f);
            } else {
                n0 = b2f_lo(un);
                n1 = b2f_hi(un);
            }
            a0 += eps1 * n0;
            a1 += eps1 * n1;
            float2 o; o.x = a0; o.y = a1;
            *(float2*)(A + (size_t)n * DD + 2 * lane) = o;
        }
    }
    __threadfence();
    grid.sync();

    // ---- phase 2: stage A -> LDS hi/lo; K-loop W1 -> acc1; stats1 ----
    int row0 = blockIdx.x * 64;
    {
        const float* g = A + (size_t)row0 * DD;   // OOB rows (last block) read ws padding; masked later
#pragma unroll
        for (int i = 0; i < 8; i++) {
            int idx = i * 1024 + tid * 4;
            float4 v = *(const float4*)(g + idx);
            int r = idx >> 7, c = idx & 127;
            ushort4v hi, lo;
            hi[0] = f2b(v.x); lo[0] = f2b(v.x - bs2f((short)hi[0]));
            hi[1] = f2b(v.y); lo[1] = f2b(v.y - bs2f((short)hi[1]));
            hi[2] = f2b(v.z); lo[2] = f2b(v.z - bs2f((short)hi[2]));
            hi[3] = f2b(v.w); lo[3] = f2b(v.w - bs2f((short)hi[3]));
            *(ushort4v*)(Ahi + r * LDK + c) = hi;
            *(ushort4v*)(Alo + r * LDK + c) = lo;
        }
    }
    __syncthreads();

    int quad = lane >> 4, l16 = lane & 15;
    int bank = blockIdx.x & (NBANK - 1);
    floatx4 acc1[4][2];
#pragma unroll
    for (int rt = 0; rt < 4; rt++)
#pragma unroll
        for (int nt = 0; nt < 2; nt++) acc1[rt][nt] = (floatx4){0.f, 0.f, 0.f, 0.f};
    {
        const short8* bhp = (const short8*)wf1_hi;
        const short8* blp = (const short8*)wf1_lo;
#pragma unroll
        for (int kt = 0; kt < 4; kt++) {
            short8 ahi[4], alo[4];
            int kb = kt * 32 + quad * 8;
#pragma unroll
            for (int rt = 0; rt < 4; rt++) {
                int ro = (rt * 16 + l16) * LDK + kb;
                ahi[rt] = *(const short8*)(Ahi + ro);
                alo[rt] = *(const short8*)(Alo + ro);
            }
#pragma unroll
            for (int nt = 0; nt < 2; nt++) {
                int ntg = wid * 2 + nt;
                short8 bhi = bhp[(kt * 8 + ntg) * 64 + lane];
                short8 blo = blp[(kt * 8 + ntg) * 64 + lane];
#pragma unroll
                for (int rt = 0; rt < 4; rt++) {
                    acc1[rt][nt] = __builtin_amdgcn_mfma_f32_16x16x32_bf16(ahi[rt], bhi, acc1[rt][nt], 0, 0, 0);
                    acc1[rt][nt] = __builtin_amdgcn_mfma_f32_16x16x32_bf16(alo[rt], bhi, acc1[rt][nt], 0, 0, 0);
                    acc1[rt][nt] = __builtin_amdgcn_mfma_f32_16x16x32_bf16(ahi[rt], blo, acc1[rt][nt], 0, 0, 0);
                }
            }
        }
    }
    // stats1 on z1 = acc1 + bias1 (z1 itself stays in registers)
#pragma unroll
    for (int nt = 0; nt < 2; nt++) {
        int col = (wid * 2 + nt) * 16 + l16;
        float bv = bias1[col];
        float s = 0.f, q = 0.f;
#pragma unroll
        for (int rt = 0; rt < 4; rt++) {
#pragma unroll
            for (int v = 0; v < 4; v++) {
                int r = row0 + rt * 16 + quad * 4 + v;
                float o = acc1[rt][nt][v] + bv;
                if (r < GN) { s += o; q += o * o; }
            }
        }
        s += __shfl_xor(s, 16); s += __shfl_xor(s, 32);
        q += __shfl_xor(q, 16); q += __shfl_xor(q, 32);
        if (lane < 16) {
            atomicAdd(&stats1[bank * 256 + col], s);
            atomicAdd(&stats1[bank * 256 + 128 + col], q);
        }
    }
    __threadfence();
    grid.sync();

    // ---- phase 3: bn1 coefs; rewrite LDS with relu(bn1(z1)) hi/lo ----
    if (tid < DD) {
        float s = 0.f, q = 0.f;
#pragma unroll
        for (int bk = 0; bk < NBANK; bk++) {
            s += stats1[bk * 256 + tid];
            q += stats1[bk * 256 + 128 + tid];
        }
        float m = s * (1.0f / GN);
        float v = q * (1.0f / GN) - m * m;
        float sc = bn1_g[tid] * rsqrtf(v + 1e-5f);
        sc_s[tid] = sc;
        tr_s[tid] = bn1_b[tid] - m * sc;
    }
    __syncthreads();
#pragma unroll
    for (int nt = 0; nt < 2; nt++) {
        int col = (wid * 2 + nt) * 16 + l16;
        float bv = bias1[col];
        float sc = sc_s[col], tr = tr_s[col];
#pragma unroll
        for (int rt = 0; rt < 4; rt++) {
#pragma unroll
            for (int v = 0; v < 4; v++) {
                int lr = rt * 16 + quad * 4 + v;
                float o = acc1[rt][nt][v] + bv;
                float h = fmaxf(o * sc + tr, 0.f);
                unsigned short hi = f2b(h);
                Ahi[lr * LDK + col] = hi;
                Alo[lr * LDK + col] = f2b(h - bs2f((short)hi));
            }
        }
    }
    __syncthreads();

    // ---- phase 4: K-loop W2 -> acc2; z2 epilogue ----
    floatx4 acc2[4][2];
#pragma unroll
    for (int rt = 0; rt < 4; rt++)
#pragma unroll
        for (int nt = 0; nt < 2; nt++) acc2[rt][nt] = (floatx4){0.f, 0.f, 0.f, 0.f};
    {
        const short8* bhp = (const short8*)wf2_hi;
        const short8* blp = (const short8*)wf2_lo;
#pragma unroll
        for (int kt = 0; kt < 4; kt++) {
            short8 ahi[4], alo[4];
            int kb = kt * 32 + quad * 8;
#pragma unroll
            for (int rt = 0; rt < 4; rt++) {
                int ro = (rt * 16 + l16) * LDK + kb;
                ahi[rt] = *(const short8*)(Ahi + ro);
                alo[rt] = *(const short8*)(Alo + ro);
            }
#pragma unroll
            for (int nt = 0; nt < 2; nt++) {
                int ntg = wid * 2 + nt;
                short8 bhi = bhp[(kt * 8 + ntg) * 64 + lane];
                short8 blo = blp[(kt * 8 + ntg) * 64 + lane];
#pragma unroll
                for (int rt = 0; rt < 4; rt++) {
                    acc2[rt][nt] = __builtin_amdgcn_mfma_f32_16x16x32_bf16(ahi[rt], bhi, acc2[rt][nt], 0, 0, 0);
                    acc2[rt][nt] = __builtin_amdgcn_mfma_f32_16x16x32_bf16(alo[rt], bhi, acc2[rt][nt], 0, 0, 0);
                    acc2[rt][nt] = __builtin_amdgcn_mfma_f32_16x16x32_bf16(ahi[rt], blo, acc2[rt][nt], 0, 0, 0);
                }
            }
        }
    }
#pragma unroll
    for (int nt = 0; nt < 2; nt++) {
        int col = (wid * 2 + nt) * 16 + l16;
        float bv = bias2[col];
        float s = 0.f, q = 0.f;
#pragma unroll
        for (int rt = 0; rt < 4; rt++) {
#pragma unroll
            for (int v = 0; v < 4; v++) {
                int r = row0 + rt * 16 + quad * 4 + v;
                float o = acc2[rt][nt][v] + bv;
                if (r < GN) {
                    s += o; q += o * o;
                    if (!LAST) z2bf[(size_t)r * DD + col] = f2b(o);
                }
            }
        }
        s += __shfl_xor(s, 16); s += __shfl_xor(s, 32);
        q += __shfl_xor(q, 16); q += __shfl_xor(q, 32);
        if (lane < 16) {
            atomicAdd(&stats2[bank * 256 + col], s);
            atomicAdd(&stats2[bank * 256 + 128 + col], q);
        }
    }

    if (LAST) {
        __threadfence();
        grid.sync();
        if (tid < DD) {
            float s = 0.f, q = 0.f;
#pragma unroll
            for (int bk = 0; bk < NBANK; bk++) {
                s += stats2[bk * 256 + tid];
                q += stats2[bk * 256 + 128 + tid];
            }
            float m = s * (1.0f / GN);
            float v = q * (1.0f / GN) - m * m;
            float sc = bn2_g[tid] * rsqrtf(v + 1e-5f);
            sc_s[tid] = sc;
            tr_s[tid] = bn2_b[tid] - m * sc;
        }
        __syncthreads();
#pragma unroll
        for (int nt = 0; nt < 2; nt++) {
            int col = (wid * 2 + nt) * 16 + l16;
            float bv = bias2[col];
            float sc = sc_s[col], tr = tr_s[col];
#pragma unroll
            for (int rt = 0; rt < 4; rt++) {
#pragma unroll
                for (int v = 0; v < 4; v++) {
                    int r = row0 + rt * 16 + quad * 4 + v;
                    if (r < GN) {
                        float o = acc2[rt][nt][v] + bv;
                        out[(size_t)r * DD + col] = o * sc + tr;
                    }
                }
            }
        }
    }
}

// ================================================================ legacy fallback path
// (R3/R7 proven kernels; used only if hipLaunchCooperativeKernel errors)
template <int BN>
__global__ __launch_bounds__(256) void edge_kernel(
    const int4* __restrict__ ep,
    const unsigned short* __restrict__ tbl_bl, const unsigned short* __restrict__ tbl_pr,
    const unsigned short* __restrict__ tbl_bond,
    const unsigned short* __restrict__ hsrc, const int* __restrict__ row_start,
    const float* __restrict__ eps_gin, int layer,
    const float* __restrict__ stats_prev, const float* __restrict__ g_prev,
    const float* __restrict__ b_prev,
    float* __restrict__ A)
{
    __shared__ float sc_s[DD], tr_s[DD];
    int tid = threadIdx.x;
    if (BN) {
        if (tid < DD) {
            float s = 0.f, q = 0.f;
#pragma unroll
            for (int bk = 0; bk < NBANK; bk++) {
                s += stats_prev[bk * 256 + tid];
                q += stats_prev[bk * 256 + 128 + tid];
            }
            float m = s * (1.0f / GN);
            float v = q * (1.0f / GN) - m * m;
            float sc = g_prev[tid] * rsqrtf(v + 1e-5f);
            sc_s[tid] = sc;
            tr_s[tid] = b_prev[tid] - m * sc;
        }
        __syncthreads();
    }
    int wid = __builtin_amdgcn_readfirstlane(tid >> 6);
    int lane = tid & 63;
    float sc0 = 1.f, tr0 = 0.f, sc1 = 1.f, tr1 = 0.f;
    if (BN) {
        sc0 = sc_s[2 * lane];     tr0 = tr_s[2 * lane];
        sc1 = sc_s[2 * lane + 1]; tr1 = tr_s[2 * lane + 1];
    }
    int n = blockIdx.x * 4 + wid;
    int s0 = __builtin_amdgcn_readfirstlane(row_start[n]);
    int s1 = __builtin_amdgcn_readfirstlane(row_start[n + 1]);
    const unsigned int* hu = (const unsigned int*)hsrc;
    const unsigned int* tb = (const unsigned int*)tbl_bl;
    const unsigned int* tp = (const unsigned int*)tbl_pr;
    const unsigned int* tg = (const unsigned int*)tbl_bond;
    float a0 = 0.f, a1 = 0.f;
    for (int p = s0; p < s1; p++) {
        int4 m0 = ep[p];
        unsigned int ub0 = tb[(size_t)(m0.y & 0xffff) * 64 + lane];
        unsigned int up0 = tp[(size_t)((unsigned)m0.y >> 16) * 64 + lane];
        unsigned int ug0 = tg[(size_t)m0.z * 64 + lane];
        unsigned int uh0 = hu[(size_t)m0.x * 64 + lane];
        float h00, h01;
        if (BN) {
            h00 = fmaxf(fmaf(b2f_lo(uh0), sc0, tr0), 0.f);
            h01 = fmaxf(fmaf(b2f_hi(uh0), sc1, tr1), 0.f);
        } else {
            h00 = b2f_lo(uh0);
            h01 = b2f_hi(uh0);
        }
        a0 += fmaxf(h00 + b2f_lo(ub0) + b2f_lo(up0) + b2f_lo(ug0), 0.f);
        a1 += fmaxf(h01 + b2f_hi(ub0) + b2f_hi(up0) + b2f_hi(ug0), 0.f);
    }
    float eps1 = 1.f + eps_gin[layer];
    unsigned int un = hu[(size_t)n * 64 + lane];
    float n0, n1;
    if (BN) {
        n0 = fmaxf(fmaf(b2f_lo(un), sc0, tr0), 0.f);
        n1 = fmaxf(fmaf(b2f_hi(un), sc1, tr1), 0.f);
    } else {
        n0 = b2f_lo(un);
        n1 = b2f_hi(un);
    }
    a0 += eps1 * n0;
    a1 += eps1 * n1;
    float2 o; o.x = a0; o.y = a1;
    *(float2*)(A + (size_t)n * DD + 2 * lane) = o;
}

template <int MODE>
__global__ __launch_bounds__(256) void gemm_kernel(
    const float* __restrict__ Asrc,
    const unsigned short* __restrict__ wf_hi, const unsigned short* __restrict__ wf_lo,
    const float* __restrict__ bias,
    unsigned short* __restrict__ Cbf, float* __restrict__ Cf32, int out_bf16,
    const float* __restrict__ stats_in, const float* __restrict__ bn_g,
    const float* __restrict__ bn_b, float* __restrict__ stats_out)
{
    __shared__ unsigned short Ahi[64 * LDK];
    __shared__ unsigned short Alo[64 * LDK];
    __shared__ float sc_s[DD], tr_s[DD];
    int tid = threadIdx.x, wid = tid >> 6, lane = tid & 63;
    int row0 = blockIdx.x * 64;
    if (MODE == 1) {
        if (tid < DD) {
            float s = 0.f, q = 0.f;
#pragma unroll
            for (int bk = 0; bk < NBANK; bk++) {
                s += stats_in[bk * 256 + tid];
                q += stats_in[bk * 256 + 128 + tid];
            }
            float m = s * (1.0f / GN);
            float v = q * (1.0f / GN) - m * m;
            float sc = bn_g[tid] * rsqrtf(v + 1e-5f);
            sc_s[tid] = sc;
            tr_s[tid] = bn_b[tid] - m * sc;
        }
        __syncthreads();
    }
    {
        const float* g = Asrc + (size_t)row0 * DD;
#pragma unroll
        for (int i = 0; i < 8; i++) {
            int idx = i * 1024 + tid * 4;
            float4 v = *(const float4*)(g + idx);
            int r = idx >> 7, c = idx & 127;
            if (MODE == 1) {
                v.x = fmaxf(v.x * sc_s[c]     + tr_s[c],     0.f);
                v.y = fmaxf(v.y * sc_s[c + 1] + tr_s[c + 1], 0.f);
                v.z = fmaxf(v.z * sc_s[c + 2] + tr_s[c + 2], 0.f);
                v.w = fmaxf(v.w * sc_s[c + 3] + tr_s[c + 3], 0.f);
            }
            ushort4v hi, lo;
            hi[0] = f2b(v.x); lo[0] = f2b(v.x - bs2f((short)hi[0]));
            hi[1] = f2b(v.y); lo[1] = f2b(v.y - bs2f((short)hi[1]));
            hi[2] = f2b(v.z); lo[2] = f2b(v.z - bs2f((short)hi[2]));
            hi[3] = f2b(v.w); lo[3] = f2b(v.w - bs2f((short)hi[3]));
            *(ushort4v*)(Ahi + r * LDK + c) = hi;
            *(ushort4v*)(Alo + r * LDK + c) = lo;
        }
    }
    __syncthreads();
    int quad = lane >> 4, l16 = lane & 15;
    floatx4 acc[4][2];
#pragma unroll
    for (int rt = 0; rt < 4; rt++)
#pragma unroll
        for (int nt = 0; nt < 2; nt++) acc[rt][nt] = (floatx4){0.f, 0.f, 0.f, 0.f};
    const short8* bhp = (const short8*)wf_hi;
    const short8* blp = (const short8*)wf_lo;
#pragma unroll
    for (int kt = 0; kt < 4; kt++) {
        short8 ahi[4], alo[4];
        int kb = kt * 32 + quad * 8;
#pragma unroll
        for (int rt = 0; rt < 4; rt++) {
            int ro = (rt * 16 + l16) * LDK + kb;
            ahi[rt] = *(const short8*)(Ahi + ro);
            alo[rt] = *(const short8*)(Alo + ro);
        }
#pragma unroll
        for (int nt = 0; nt < 2; nt++) {
            int ntg = wid * 2 + nt;
            short8 bhi = bhp[(kt * 8 + ntg) * 64 + lane];
            short8 blo = blp[(kt * 8 + ntg) * 64 + lane];
#pragma unroll
            for (int rt = 0; rt < 4; rt++) {
                acc[rt][nt] = __builtin_amdgcn_mfma_f32_16x16x32_bf16(ahi[rt], bhi, acc[rt][nt], 0, 0, 0);
                acc[rt][nt] = __builtin_amdgcn_mfma_f32_16x16x32_bf16(alo[rt], bhi, acc[rt][nt], 0, 0, 0);
                acc[rt][nt] = __builtin_amdgcn_mfma_f32_16x16x32_bf16(ahi[rt], blo, acc[rt][nt], 0, 0, 0);
            }
        }
    }
    int bank = blockIdx.x & (NBANK - 1);
#pragma unroll
    for (int nt = 0; nt < 2; nt++) {
        int col = (wid * 2 + nt) * 16 + l16;
        float bv = bias[col];
        float s = 0.f, q = 0.f;
#pragma unroll
        for (int rt = 0; rt < 4; rt++) {
#pragma unroll
            for (int v = 0; v < 4; v++) {
                int r = row0 + rt * 16 + quad * 4 + v;
                float o = acc[rt][nt][v] + bv;
                if (r < GN) {
                    s += o; q += o * o;
                    if (MODE == 1 && out_bf16) Cbf[(size_t)r * DD + col] = f2b(o);
                    else                       Cf32[(size_t)r * DD + col] = o;
                }
            }
        }
        s += __shfl_xor(s, 16); s += __shfl_xor(s, 32);
        q += __shfl_xor(q, 16); q += __shfl_xor(q, 32);
        if (lane < 16) {
            atomicAdd(&stats_out[bank * 256 + col], s);
            atomicAdd(&stats_out[bank * 256 + 128 + col], q);
        }
    }
}

__global__ __launch_bounds__(256) void bn_apply_kernel(
    const float* __restrict__ Z, const float* __restrict__ stats2,
    const float* __restrict__ g, const float* __restrict__ b,
    float* __restrict__ fout)
{
    __shared__ float sc_s[DD], tr_s[DD];
    int tid = threadIdx.x;
    if (tid < DD) {
        float s = 0.f, q = 0.f;
#pragma unroll
        for (int bk = 0; bk < NBANK; bk++) {
            s += stats2[bk * 256 + tid];
            q += stats2[bk * 256 + 128 + tid];
        }
        float m = s * (1.0f / GN);
        float v = q * (1.0f / GN) - m * m;
        float sc = g[tid] * rsqrtf(v + 1e-5f);
        sc_s[tid] = sc;
        tr_s[tid] = b[tid] - m * sc;
    }
    __syncthreads();
    const int total = GN * DD;
    for (int t = blockIdx.x * 256 + tid; t < total; t += gridDim.x * 256) {
        int c = t & 127;
        fout[t] = Z[t] * sc_s[c] + tr_s[c];
    }
}

// ---------------------------------------------------------------- host launcher
extern "C" void kernel_launch(void* const* d_in, const int* in_sizes, int n_in,
                              void* d_out, int out_size, void* d_ws, size_t ws_size,
                              hipStream_t stream)
{
    const int*   x        = (const int*)d_in[0];
    const int*   ei       = (const int*)d_in[1];
    const int*   eai      = (const int*)d_in[2];
    const float* eaf      = (const float*)d_in[3];
    const int*   atom_off = (const int*)d_in[4];
    const int*   bond_off = (const int*)d_in[5];
    const float* atom_emb = (const float*)d_in[6];
    const float* bond_emb = (const float*)d_in[7];
    const float* W_bl     = (const float*)d_in[8];
    const float* b_bl     = (const float*)d_in[9];
    const float* W_pr     = (const float*)d_in[10];
    const float* b_pr     = (const float*)d_in[11];
    const float* W1       = (const float*)d_in[12];
    const float* b1       = (const float*)d_in[13];
    const float* bn1g     = (const float*)d_in[14];
    const float* bn1b     = (const float*)d_in[15];
    const float* W2       = (const float*)d_in[16];
    const float* b2       = (const float*)d_in[17];
    const float* eps_gin  = (const float*)d_in[18];
    const float* bng      = (const float*)d_in[19];
    const float* bnb      = (const float*)d_in[20];
    float* out = (float*)d_out;

    char* p = (char*)d_ws;
    unsigned short* h_bf  = (unsigned short*)p;  p += (size_t)GN * DD * 2;   // atom output (layer 0)
    unsigned short* z2_bf = (unsigned short*)p;  p += (size_t)GN * DD * 2;   // raw z2 (layers 0-3)
    float* A              = (float*)p;           p += (size_t)GN * DD * 4;   // edge output
    float* z1             = (float*)p;           p += (size_t)GN * DD * 4;   // legacy only; OOB pad for A
    float* z2f            = (float*)p;           p += (size_t)GN * DD * 4;   // legacy only
    unsigned short* tbl_bl   = (unsigned short*)p;  p += (size_t)5 * (TQ + 1) * DD * 2;
    unsigned short* tbl_pr   = (unsigned short*)p;  p += (size_t)5 * (TQ + 1) * DD * 2;
    unsigned short* tbl_bond = (unsigned short*)p;  p += (size_t)5 * NBOND * DD * 2;
    unsigned short* wf_hi    = (unsigned short*)p;  p += (size_t)10 * 16384 * 2;
    unsigned short* wf_lo    = (unsigned short*)p;  p += (size_t)10 * 16384 * 2;
    float* stats_all = (float*)p;  p += (size_t)10 * SSET * 4;   // [layer][{1,2}][bank][256]
    int* count    = (int*)p;    p += (size_t)GN * 4;
    int* fill     = (int*)p;    p += (size_t)GN * 4;
    int* row_start= (int*)p;    p += (size_t)(GN + 1) * 4;
    int* blocksum = (int*)p;    p += (size_t)SCB * 4;
    int* blockoff = (int*)p;    p += (size_t)SCB * 4;
    p = (char*)(((size_t)p + 15) & ~(size_t)15);
    int4* ep      = (int4*)p;   p += (size_t)GE * 16;

    hipMemsetAsync(count, 0, (size_t)GN * 4, stream);
    hipMemsetAsync(fill,  0, (size_t)GN * 4, stream);
    hipMemsetAsync(stats_all, 0, (size_t)10 * SSET * 4, stream);

    hist_kernel<<<(GE + 255) / 256, 256, 0, stream>>>(ei, count);
    scan1_kernel<<<SCB, 1024, 0, stream>>>(count, row_start, blocksum);
    scan2_kernel<<<1, 64, 0, stream>>>(blocksum, blockoff);
    scan3_kernel<<<SCB, 1024, 0, stream>>>(row_start, blockoff);
    scatter_kernel<<<(GE + 255) / 256, 256, 0, stream>>>(ei, eai, eaf, row_start, fill, ep);
    atom_kernel<<<(GN * DD + 255) / 256, 256, 0, stream>>>(x, atom_off, atom_emb, h_bf);
    wfrag_kernel<<<80, 256, 0, stream>>>(W1, W2, wf_hi, wf_lo);
    tables_kernel<<<5 * TROWS, 128, 0, stream>>>(
        W_bl, b_bl, W_pr, b_pr, bond_emb, bond_off, tbl_bl, tbl_pr, tbl_bond);

    bool legacy = false;
    for (int l = 0; l < 5; l++) {
        float* stats1 = stats_all + (size_t)(2 * l + 0) * SSET;
        float* stats2 = stats_all + (size_t)(2 * l + 1) * SSET;
        float* stats2_prev = stats_all + (size_t)(2 * (l - 1) + 1) * SSET;

        if (!legacy) {
            const int4* ep_a = ep;
            const unsigned short* tbl_bl_a = tbl_bl + (size_t)l * (TQ + 1) * DD;
            const unsigned short* tbl_pr_a = tbl_pr + (size_t)l * (TQ + 1) * DD;
            const unsigned short* tbl_bond_a = tbl_bond + (size_t)l * NBOND * DD;
            const unsigned short* hsrc_a = (l == 0) ? h_bf : z2_bf;
            const int* rs_a = row_start;
            const float* eps_a = eps_gin;
            int layer_a = l;
            const float* sp_a = (l > 0) ? stats2_prev : stats_all;
            const float* gp_a = bng + (size_t)(l > 0 ? l - 1 : 0) * DD;
            const float* bp_a = bnb + (size_t)(l > 0 ? l - 1 : 0) * DD;
            float* A_a = A;
            const unsigned short* w1h_a = wf_hi + (size_t)(l * 2 + 0) * 16384;
            const unsigned short* w1l_a = wf_lo + (size_t)(l * 2 + 0) * 16384;
            const unsigned short* w2h_a = wf_hi + (size_t)(l * 2 + 1) * 16384;
            const unsigned short* w2l_a = wf_lo + (size_t)(l * 2 + 1) * 16384;
            const float* b1_a = b1 + (size_t)l * DD;
            const float* b2_a = b2 + (size_t)l * DD;
            float* s1_a = stats1;
            float* s2_a = stats2;
            const float* bn1g_a = bn1g + (size_t)l * DD;
            const float* bn1b_a = bn1b + (size_t)l * DD;
            const float* bn2g_a = bng + (size_t)l * DD;
            const float* bn2b_a = bnb + (size_t)l * DD;
            unsigned short* z2_a = z2_bf;
            float* out_a = out;
            void* args[] = {
                (void*)&ep_a, (void*)&tbl_bl_a, (void*)&tbl_pr_a, (void*)&tbl_bond_a,
                (void*)&hsrc_a, (void*)&rs_a, (void*)&eps_a, (void*)&layer_a,
                (void*)&sp_a, (void*)&gp_a, (void*)&bp_a, (void*)&A_a,
                (void*)&w1h_a, (void*)&w1l_a, (void*)&w2h_a, (void*)&w2l_a,
                (void*)&b1_a, (void*)&b2_a, (void*)&s1_a, (void*)&s2_a,
                (void*)&bn1g_a, (void*)&bn1b_a, (void*)&bn2g_a, (void*)&bn2b_a,
                (void*)&z2_a, (void*)&out_a };
            hipError_t e;
            if (l == 0)
                e = hipLaunchCooperativeKernel((const void*)&layer_kernel<1, 0>,
                                               dim3(NB), dim3(256), args, 0, stream);
            else if (l < 4)
                e = hipLaunchCooperativeKernel((const void*)&layer_kernel<0, 0>,
                                               dim3(NB), dim3(256), args, 0, stream);
            else
                e = hipLaunchCooperativeKernel((const void*)&layer_kernel<0, 1>,
                                               dim3(NB), dim3(256), args, 0, stream);
            if (e != hipSuccess) legacy = true;   // fall through to legacy for this + remaining layers
        }

        if (legacy) {
            if (l == 0) {
                edge_kernel<0><<<GN / 4, 256, 0, stream>>>(
                    ep, tbl_bl, tbl_pr, tbl_bond,
                    h_bf, row_start, eps_gin, l,
                    stats_all, bng, bnb, A);
            } else {
                edge_kernel<1><<<GN / 4, 256, 0, stream>>>(
                    ep,
                    tbl_bl + (size_t)l * (TQ + 1) * DD,
                    tbl_pr + (size_t)l * (TQ + 1) * DD,
                    tbl_bond + (size_t)l * NBOND * DD,
                    z2_bf, row_start, eps_gin, l,
                    stats2_prev,
                    bng + (size_t)(l - 1) * DD,
                    bnb + (size_t)(l - 1) * DD,
                    A);
            }
            gemm_kernel<0><<<NB, 256, 0, stream>>>(
                A, wf_hi + (size_t)(l * 2 + 0) * 16384, wf_lo + (size_t)(l * 2 + 0) * 16384,
                b1 + (size_t)l * DD, nullptr, z1, 0,
                nullptr, nullptr, nullptr, stats1);
            gemm_kernel<1><<<NB, 256, 0, stream>>>(
                z1, wf_hi + (size_t)(l * 2 + 1) * 16384, wf_lo + (size_t)(l * 2 + 1) * 16384,
                b2 + (size_t)l * DD, z2_bf, z2f, (l < 4) ? 1 : 0,
                stats1, bn1g + (size_t)l * DD, bn1b + (size_t)l * DD, stats2);
        }
    }

    if (legacy) {
        bn_apply_kernel<<<1024, 256, 0, stream>>>(
            z2f, stats_all + (size_t)9 * SSET, bng + (size_t)4 * DD, bnb + (size_t)4 * DD, out);
    }
}

// Round 9
// 644.406 us; speedup vs baseline: 3.7462x; 3.7462x over previous
//
#include <hip/hip_runtime.h>
#include <hip/hip_bf16.h>

#define GN 50000
#define GE 600000
#define DD 128
#define TQ 2048          // RBF table quantization (2049 rows per layer; halved from 4096:
                         // x-err <= 2.4e-4 * max-slope 2.71 -> ~3e-4 edge error, invisible
                         // vs 0.078 absmax; halves table build + 2x better L2 residency)
#define NBOND 2268       // 12*27*7 bond combo rows
#define TROWS (2*(TQ+1) + NBOND)   // table-build blocks per layer
#define SCB 49           // scan blocks of 1024 -> 49*1024 = 50176 >= GN+1
#define NBANK 16         // stats banks
#define SSET (NBANK*256) // floats per stats set: [bank][0..127 sum | 128..255 sumsq]
#define NB 782           // (GN+63)/64 row tiles
#define LDK 136          // LDS bf16 A-tile stride: 128+8 shorts -> 2-way only (free, m136)

typedef __attribute__((ext_vector_type(8))) short short8;
typedef __attribute__((ext_vector_type(4))) unsigned short ushort4v;
typedef __attribute__((ext_vector_type(4))) float floatx4;

__device__ __forceinline__ unsigned short f2b(float f) {
    __hip_bfloat16 h = __float2bfloat16(f);
    return __builtin_bit_cast(unsigned short, h);
}
__device__ __forceinline__ float b2f_lo(unsigned int u) { return __uint_as_float(u << 16); }
__device__ __forceinline__ float b2f_hi(unsigned int u) { return __uint_as_float(u & 0xffff0000u); }
__device__ __forceinline__ float bs2f(short s) {
    return __uint_as_float(((unsigned int)(unsigned short)s) << 16);
}

// ---------------------------------------------------------------- atom encoder -> h (bf16)
__global__ __launch_bounds__(256) void atom_kernel(
    const int* __restrict__ x, const int* __restrict__ atom_off,
    const float* __restrict__ atom_emb, unsigned short* __restrict__ h)
{
    int t = blockIdx.x * 256 + threadIdx.x;
    if (t >= GN * DD) return;
    int n = t >> 7, d = t & 127;
    float s = 0.f;
#pragma unroll
    for (int f = 0; f < 9; f++) {
        int idx = x[n * 9 + f] + atom_off[f];
        s += atom_emb[idx * DD + d];
    }
    h[t] = f2b(s);
}

// ---------------------------------------------------------------- CSR build
__global__ __launch_bounds__(256) void hist_kernel(const int* __restrict__ ei, int* __restrict__ count)
{
    int e = blockIdx.x * 256 + threadIdx.x;
    if (e < GE) atomicAdd(&count[ei[GE + e]], 1);
}

__global__ __launch_bounds__(1024) void scan1_kernel(
    const int* __restrict__ count, int* __restrict__ row_start, int* __restrict__ blocksum)
{
    __shared__ int sh[1024];
    int t = threadIdx.x;
    int idx = blockIdx.x * 1024 + t;
    int v = (idx < GN) ? count[idx] : 0;
    sh[t] = v;
    __syncthreads();
    for (int off = 1; off < 1024; off <<= 1) {
        int u = (t >= off) ? sh[t - off] : 0;
        __syncthreads();
        sh[t] += u;
        __syncthreads();
    }
    if (idx <= GN) row_start[idx] = (t == 0) ? 0 : sh[t - 1];   // local exclusive
    if (t == 1023) blocksum[blockIdx.x] = sh[1023];
}

__global__ __launch_bounds__(64) void scan2_kernel(
    const int* __restrict__ blocksum, int* __restrict__ blockoff)
{
    int t = threadIdx.x;
    int v = (t < SCB) ? blocksum[t] : 0;
#pragma unroll
    for (int off = 1; off < 64; off <<= 1) {
        int u = __shfl_up(v, off);
        if (t >= off) v += u;
    }
    int e = __shfl_up(v, 1);
    if (t == 0) e = 0;
    if (t < SCB) blockoff[t] = e;
}

__global__ __launch_bounds__(1024) void scan3_kernel(
    int* __restrict__ row_start, const int* __restrict__ blockoff)
{
    int idx = blockIdx.x * 1024 + threadIdx.x;
    if (idx <= GN) row_start[idx] += blockoff[blockIdx.x];
}

// scatter + pack per-edge metadata {src, q1|q2<<16, bondcombo, 0} in CSR order
__global__ __launch_bounds__(256) void scatter_kernel(
    const int* __restrict__ ei, const int* __restrict__ eai, const float* __restrict__ eaf,
    const int* __restrict__ row_start, int* __restrict__ fill, int4* __restrict__ ep)
{
    int e = blockIdx.x * 256 + threadIdx.x;
    if (e < GE) {
        int d = ei[GE + e];
        int p = row_start[d] + atomicAdd(&fill[d], 1);
        int src = ei[e];
        float x1 = eaf[2 * e], x2 = eaf[2 * e + 1];
        int q1 = (int)(x1 * (float)TQ + 0.5f); q1 = min(max(q1, 0), TQ);
        int q2 = (int)(x2 * (float)TQ + 0.5f); q2 = min(max(q2, 0), TQ);
        int b0 = eai[3 * e], b1 = eai[3 * e + 1], b2 = eai[3 * e + 2];
        ep[p] = make_int4(src, q1 | (q2 << 16), (b0 * 27 + b1) * 7 + b2, 0);
    }
}

// ---------------------------------------------------------------- tables for ALL layers (bf16)
__global__ __launch_bounds__(128) void tables_kernel(
    const float* __restrict__ W_bl, const float* __restrict__ b_bl,
    const float* __restrict__ W_pr, const float* __restrict__ b_pr,
    const float* __restrict__ bond_emb, const int* __restrict__ bond_off,
    unsigned short* __restrict__ tbl_bl, unsigned short* __restrict__ tbl_pr,
    unsigned short* __restrict__ tbl_bond)
{
    int l = blockIdx.x / TROWS;
    int b = blockIdx.x % TROWS;
    int d = threadIdx.x;
    const float* W_bl_l = W_bl + (size_t)l * 20 * DD;
    const float* W_pr_l = W_pr + (size_t)l * 20 * DD;
    const float* bemb_l = bond_emb + (size_t)l * 46 * DD;
    if (b < (TQ + 1)) {
        float xq = b * (1.0f / TQ);
        float s = b_bl[(size_t)l * DD + d] + b_pr[(size_t)l * DD + d];
#pragma unroll
        for (int k = 0; k < 20; k++) {
            float dl = xq - 0.1f * k;
            s += __expf(-10.f * dl * dl) * W_bl_l[k * DD + d];
        }
        tbl_bl[((size_t)l * (TQ + 1) + b) * DD + d] = f2b(s);
    } else if (b < 2 * (TQ + 1)) {
        int q = b - (TQ + 1);
        float xq = q * (1.0f / TQ);
        float s = 0.f;
#pragma unroll
        for (int k = 0; k < 20; k++) {
            float dl = xq - 0.05f * k;
            s += __expf(-dl * dl) * W_pr_l[k * DD + d];
        }
        tbl_pr[((size_t)l * (TQ + 1) + q) * DD + d] = f2b(s);
    } else {
        int r = b - 2 * (TQ + 1);
        int b0 = r / 189;            // 27*7
        int rem = r % 189;
        int b1 = rem / 7, b2 = rem % 7;
        tbl_bond[((size_t)l * NBOND + r) * DD + d] =
            f2b(bemb_l[(b0 + bond_off[0]) * DD + d]
              + bemb_l[(b1 + bond_off[1]) * DD + d]
              + bemb_l[(b2 + bond_off[2]) * DD + d]);
    }
}

// ---------------------------------------------------------------- W -> MFMA B-fragment hi/lo packs
__global__ __launch_bounds__(256) void wfrag_kernel(
    const float* __restrict__ W1, const float* __restrict__ W2,
    unsigned short* __restrict__ wf_hi, unsigned short* __restrict__ wf_lo)
{
    int t = blockIdx.x * 256 + threadIdx.x;    // 0..20479
    if (t >= 10 * 2048) return;
    int mat = t >> 11;
    int rem = t & 2047;
    int kt = rem >> 9;
    int rem2 = rem & 511;
    int nt = rem2 >> 6;
    int lane = rem2 & 63;
    const float* src = (mat & 1) ? (W2 + (size_t)(mat >> 1) * DD * DD)
                                 : (W1 + (size_t)(mat >> 1) * DD * DD);
    int n = nt * 16 + (lane & 15);
    int k0 = kt * 32 + (lane >> 4) * 8;
    size_t base = (size_t)mat * 16384 + (size_t)((kt * 8 + nt) * 64 + lane) * 8;
#pragma unroll
    for (int j = 0; j < 8; j++) {
        float w = src[(size_t)(k0 + j) * DD + n];
        unsigned short hi = f2b(w);
        wf_hi[base + j] = hi;
        wf_lo[base + j] = f2b(w - bs2f((short)hi));
    }
}

// ---------------------------------------------------------------- edge/aggregate (wave per node)
// R3 structure — best measured (46.9-47.5us): wave-uniform p -> s_load meta, SGPR-base
// gathers (1 dest VGPR/load), 4-edge ping-pong. Edge floor established across 4
// structural variants (R3-R6): ~47us = scattered-256B-gather BW roofline (137MB at
// ~2.9 TB/s achieved); BW 37% of streaming peak, VALU ~55%, 0 conflicts. Do not touch.
template <int BN>
__global__ __launch_bounds__(256) void edge_kernel(
    const int4* __restrict__ ep,
    const unsigned short* __restrict__ tbl_bl, const unsigned short* __restrict__ tbl_pr,
    const unsigned short* __restrict__ tbl_bond,
    const unsigned short* __restrict__ hsrc, const int* __restrict__ row_start,
    const float* __restrict__ eps_gin, int layer,
    const float* __restrict__ stats_prev, const float* __restrict__ g_prev,
    const float* __restrict__ b_prev,
    float* __restrict__ A)
{
    __shared__ float sc_s[DD], tr_s[DD];
    int tid = threadIdx.x;
    if (BN) {
        if (tid < DD) {
            float s = 0.f, q = 0.f;
#pragma unroll
            for (int bk = 0; bk < NBANK; bk++) {
                s += stats_prev[bk * 256 + tid];
                q += stats_prev[bk * 256 + 128 + tid];
            }
            float m = s * (1.0f / GN);
            float v = q * (1.0f / GN) - m * m;
            float sc = g_prev[tid] * rsqrtf(v + 1e-5f);
            sc_s[tid] = sc;
            tr_s[tid] = b_prev[tid] - m * sc;
        }
        __syncthreads();
    }

    int wid = __builtin_amdgcn_readfirstlane(tid >> 6);
    int lane = tid & 63;
    float sc0 = 1.f, tr0 = 0.f, sc1 = 1.f, tr1 = 0.f;
    if (BN) {
        sc0 = sc_s[2 * lane];     tr0 = tr_s[2 * lane];
        sc1 = sc_s[2 * lane + 1]; tr1 = tr_s[2 * lane + 1];
    }

    int n = blockIdx.x * 4 + wid;
    int s0 = __builtin_amdgcn_readfirstlane(row_start[n]);
    int s1 = __builtin_amdgcn_readfirstlane(row_start[n + 1]);
    const unsigned int* hu = (const unsigned int*)hsrc;
    const unsigned int* tb = (const unsigned int*)tbl_bl;
    const unsigned int* tp = (const unsigned int*)tbl_pr;
    const unsigned int* tg = (const unsigned int*)tbl_bond;
    float a0 = 0.f, a1 = 0.f;

    auto meta = [&](int pb, int4 (&mm)[4]) {
#pragma unroll
        for (int j = 0; j < 4; j++) mm[j] = ep[pb + j];   // uniform -> s_load
    };
    auto issue = [&](const int4 (&mm)[4], unsigned int (&ub)[4], unsigned int (&up)[4],
                     unsigned int (&ug)[4], unsigned int (&uh)[4]) {
#pragma unroll
        for (int j = 0; j < 4; j++) {
            ub[j] = tb[(size_t)(mm[j].y & 0xffff) * 64 + lane];
            up[j] = tp[(size_t)((unsigned)mm[j].y >> 16) * 64 + lane];
            ug[j] = tg[(size_t)mm[j].z * 64 + lane];
            uh[j] = hu[(size_t)mm[j].x * 64 + lane];
        }
    };
    auto consume = [&](const unsigned int (&ub)[4], const unsigned int (&up)[4],
                       const unsigned int (&ug)[4], const unsigned int (&uh)[4]) {
#pragma unroll
        for (int j = 0; j < 4; j++) {
            float h0, h1;
            if (BN) {
                h0 = fmaxf(fmaf(b2f_lo(uh[j]), sc0, tr0), 0.f);
                h1 = fmaxf(fmaf(b2f_hi(uh[j]), sc1, tr1), 0.f);
            } else {
                h0 = b2f_lo(uh[j]);
                h1 = b2f_hi(uh[j]);
            }
            a0 += fmaxf(h0 + b2f_lo(ub[j]) + b2f_lo(up[j]) + b2f_lo(ug[j]), 0.f);
            a1 += fmaxf(h1 + b2f_hi(ub[j]) + b2f_hi(up[j]) + b2f_hi(ug[j]), 0.f);
        }
    };

    int cnt = s1 - s0;
    int nfull = cnt >> 2;
    {
        int4 mA[4], mB[4];
        unsigned int ubA[4], upA[4], ugA[4], uhA[4];
        unsigned int ubB[4], upB[4], ugB[4], uhB[4];
        if (nfull > 0) {
            meta(s0, mA);
            issue(mA, ubA, upA, ugA, uhA);
            int i = 1;
            for (; i + 1 < nfull; i += 2) {
                meta(s0 + i * 4, mB);
                meta(s0 + (i + 1) * 4, mA);           // both scalar loads up front
                issue(mB, ubB, upB, ugB, uhB);        // batch i in flight
                consume(ubA, upA, ugA, uhA);          // consume batch i-1
                issue(mA, ubA, upA, ugA, uhA);        // batch i+1 in flight
                consume(ubB, upB, ugB, uhB);          // consume batch i
            }
            if (i < nfull) {
                meta(s0 + i * 4, mB);
                issue(mB, ubB, upB, ugB, uhB);
                consume(ubA, upA, ugA, uhA);
                consume(ubB, upB, ugB, uhB);
            } else {
                consume(ubA, upA, ugA, uhA);
            }
        }
    }
    // tail: < 4 edges
    for (int p = s0 + nfull * 4; p < s1; p++) {
        int4 m0 = ep[p];
        unsigned int ub0 = tb[(size_t)(m0.y & 0xffff) * 64 + lane];
        unsigned int up0 = tp[(size_t)((unsigned)m0.y >> 16) * 64 + lane];
        unsigned int ug0 = tg[(size_t)m0.z * 64 + lane];
        unsigned int uh0 = hu[(size_t)m0.x * 64 + lane];
        float h00, h01;
        if (BN) {
            h00 = fmaxf(fmaf(b2f_lo(uh0), sc0, tr0), 0.f);
            h01 = fmaxf(fmaf(b2f_hi(uh0), sc1, tr1), 0.f);
        } else {
            h00 = b2f_lo(uh0);
            h01 = b2f_hi(uh0);
        }
        a0 += fmaxf(h00 + b2f_lo(ub0) + b2f_lo(up0) + b2f_lo(ug0), 0.f);
        a1 += fmaxf(h01 + b2f_hi(ub0) + b2f_hi(up0) + b2f_hi(ug0), 0.f);
    }

    float eps1 = 1.f + eps_gin[layer];
    unsigned int un = hu[(size_t)n * 64 + lane];
    float n0, n1;
    if (BN) {
        n0 = fmaxf(fmaf(b2f_lo(un), sc0, tr0), 0.f);
        n1 = fmaxf(fmaf(b2f_hi(un), sc1, tr1), 0.f);
    } else {
        n0 = b2f_lo(un);
        n1 = b2f_hi(un);
    }
    a0 += eps1 * n0;
    a1 += eps1 * n1;
    float2 o; o.x = a0; o.y = a1;
    *(float2*)(A + (size_t)n * DD + 2 * lane) = o;
}

// ---------------------------------------------------------------- MFMA GEMM, stage-time conversion
// 64x128 tile, 782 blocks. bn (+relu) and f32->bf16 hi/lo conversion happen ONCE at
// staging; K-loop is pure ds_read_b128 + MFMA. R8 counters: MFMA busy ~2us/gemm ->
// matrix pipe is not the limit; z1 round-trip is same-XCD L2-resident (gemm2 block b
// reads gemm1 block b's rows). MODE 0: C=A@W+b (f32). MODE 1: C=relu(bn1(A))@W+b.
template <int MODE>
__global__ __launch_bounds__(256) void gemm_kernel(
    const float* __restrict__ Asrc,
    const unsigned short* __restrict__ wf_hi, const unsigned short* __restrict__ wf_lo,
    const float* __restrict__ bias,
    unsigned short* __restrict__ Cbf, float* __restrict__ Cf32, int out_bf16,
    const float* __restrict__ stats_in, const float* __restrict__ bn_g,
    const float* __restrict__ bn_b, float* __restrict__ stats_out)
{
    __shared__ unsigned short Ahi[64 * LDK];   // 17 KB
    __shared__ unsigned short Alo[64 * LDK];   // 17 KB
    __shared__ float sc_s[DD], tr_s[DD];
    int tid = threadIdx.x, wid = tid >> 6, lane = tid & 63;
    int row0 = blockIdx.x * 64;

    if (MODE == 1) {
        if (tid < DD) {
            float s = 0.f, q = 0.f;
#pragma unroll
            for (int bk = 0; bk < NBANK; bk++) {
                s += stats_in[bk * 256 + tid];
                q += stats_in[bk * 256 + 128 + tid];
            }
            float m = s * (1.0f / GN);
            float v = q * (1.0f / GN) - m * m;
            float sc = bn_g[tid] * rsqrtf(v + 1e-5f);
            sc_s[tid] = sc;
            tr_s[tid] = bn_b[tid] - m * sc;
        }
        __syncthreads();               // staging below reads sc_s/tr_s
    }

    // stage A tile: coalesced float4 loads, bn(+relu) + hi/lo split at stage time
    {
        const float* g = Asrc + (size_t)row0 * DD;   // OOB rows (last block) read ws padding; masked at store
#pragma unroll
        for (int i = 0; i < 8; i++) {
            int idx = i * 1024 + tid * 4;            // float index in row-major tile
            float4 v = *(const float4*)(g + idx);
            int r = idx >> 7, c = idx & 127;
            if (MODE == 1) {
                v.x = fmaxf(v.x * sc_s[c]     + tr_s[c],     0.f);
                v.y = fmaxf(v.y * sc_s[c + 1] + tr_s[c + 1], 0.f);
                v.z = fmaxf(v.z * sc_s[c + 2] + tr_s[c + 2], 0.f);
                v.w = fmaxf(v.w * sc_s[c + 3] + tr_s[c + 3], 0.f);
            }
            ushort4v hi, lo;
            hi[0] = f2b(v.x); lo[0] = f2b(v.x - bs2f((short)hi[0]));
            hi[1] = f2b(v.y); lo[1] = f2b(v.y - bs2f((short)hi[1]));
            hi[2] = f2b(v.z); lo[2] = f2b(v.z - bs2f((short)hi[2]));
            hi[3] = f2b(v.w); lo[3] = f2b(v.w - bs2f((short)hi[3]));
            *(ushort4v*)(Ahi + r * LDK + c) = hi;
            *(ushort4v*)(Alo + r * LDK + c) = lo;
        }
    }
    __syncthreads();

    int quad = lane >> 4, l16 = lane & 15;
    floatx4 acc[4][2];
#pragma unroll
    for (int rt = 0; rt < 4; rt++)
#pragma unroll
        for (int nt = 0; nt < 2; nt++) acc[rt][nt] = (floatx4){0.f, 0.f, 0.f, 0.f};

    const short8* bhp = (const short8*)wf_hi;
    const short8* blp = (const short8*)wf_lo;
#pragma unroll
    for (int kt = 0; kt < 4; kt++) {
        short8 ahi[4], alo[4];
        int kb = kt * 32 + quad * 8;               // bf16-element offset in row
#pragma unroll
        for (int rt = 0; rt < 4; rt++) {
            int ro = (rt * 16 + l16) * LDK + kb;
            ahi[rt] = *(const short8*)(Ahi + ro);  // 16B ds_read_b128
            alo[rt] = *(const short8*)(Alo + ro);
        }
#pragma unroll
        for (int nt = 0; nt < 2; nt++) {
            int ntg = wid * 2 + nt;
            short8 bhi = bhp[(kt * 8 + ntg) * 64 + lane];
            short8 blo = blp[(kt * 8 + ntg) * 64 + lane];
#pragma unroll
            for (int rt = 0; rt < 4; rt++) {
                acc[rt][nt] = __builtin_amdgcn_mfma_f32_16x16x32_bf16(ahi[rt], bhi, acc[rt][nt], 0, 0, 0);
                acc[rt][nt] = __builtin_amdgcn_mfma_f32_16x16x32_bf16(alo[rt], bhi, acc[rt][nt], 0, 0, 0);
                acc[rt][nt] = __builtin_amdgcn_mfma_f32_16x16x32_bf16(ahi[rt], blo, acc[rt][nt], 0, 0, 0);
            }
        }
    }

    // epilogue: bias, store, banked stats (C/D layout: col=lane&15, row=quad*4+reg)
    int bank = blockIdx.x & (NBANK - 1);
#pragma unroll
    for (int nt = 0; nt < 2; nt++) {
        int col = (wid * 2 + nt) * 16 + l16;
        float bv = bias[col];
        float s = 0.f, q = 0.f;
#pragma unroll
        for (int rt = 0; rt < 4; rt++) {
#pragma unroll
            for (int v = 0; v < 4; v++) {
                int r = row0 + rt * 16 + quad * 4 + v;
                float o = acc[rt][nt][v] + bv;
                if (r < GN) {
                    s += o; q += o * o;
                    if (MODE == 1 && out_bf16) Cbf[(size_t)r * DD + col] = f2b(o);
                    else                       Cf32[(size_t)r * DD + col] = o;
                }
            }
        }
        s += __shfl_xor(s, 16); s += __shfl_xor(s, 32);
        q += __shfl_xor(q, 16); q += __shfl_xor(q, 32);
        if (lane < 16) {
            atomicAdd(&stats_out[bank * 256 + col], s);
            atomicAdd(&stats_out[bank * 256 + 128 + col], q);
        }
    }
}

// ---------------------------------------------------------------- BN2 apply, layer 4 only (f32 out)
__global__ __launch_bounds__(256) void bn_apply_kernel(
    const float* __restrict__ Z, const float* __restrict__ stats2,
    const float* __restrict__ g, const float* __restrict__ b,
    float* __restrict__ fout)
{
    __shared__ float sc_s[DD], tr_s[DD];
    int tid = threadIdx.x;
    if (tid < DD) {
        float s = 0.f, q = 0.f;
#pragma unroll
        for (int bk = 0; bk < NBANK; bk++) {
            s += stats2[bk * 256 + tid];
            q += stats2[bk * 256 + 128 + tid];
        }
        float m = s * (1.0f / GN);
        float v = q * (1.0f / GN) - m * m;
        float sc = g[tid] * rsqrtf(v + 1e-5f);
        sc_s[tid] = sc;
        tr_s[tid] = b[tid] - m * sc;
    }
    __syncthreads();
    const int total = GN * DD;
    for (int t = blockIdx.x * 256 + tid; t < total; t += gridDim.x * 256) {
        int c = t & 127;
        fout[t] = Z[t] * sc_s[c] + tr_s[c];
    }
}

// ---------------------------------------------------------------- host launcher
extern "C" void kernel_launch(void* const* d_in, const int* in_sizes, int n_in,
                              void* d_out, int out_size, void* d_ws, size_t ws_size,
                              hipStream_t stream)
{
    const int*   x        = (const int*)d_in[0];
    const int*   ei       = (const int*)d_in[1];
    const int*   eai      = (const int*)d_in[2];
    const float* eaf      = (const float*)d_in[3];
    const int*   atom_off = (const int*)d_in[4];
    const int*   bond_off = (const int*)d_in[5];
    const float* atom_emb = (const float*)d_in[6];
    const float* bond_emb = (const float*)d_in[7];
    const float* W_bl     = (const float*)d_in[8];
    const float* b_bl     = (const float*)d_in[9];
    const float* W_pr     = (const float*)d_in[10];
    const float* b_pr     = (const float*)d_in[11];
    const float* W1       = (const float*)d_in[12];
    const float* b1       = (const float*)d_in[13];
    const float* bn1g     = (const float*)d_in[14];
    const float* bn1b     = (const float*)d_in[15];
    const float* W2       = (const float*)d_in[16];
    const float* b2       = (const float*)d_in[17];
    const float* eps_gin  = (const float*)d_in[18];
    const float* bng      = (const float*)d_in[19];
    const float* bnb      = (const float*)d_in[20];
    float* out = (float*)d_out;

    char* p = (char*)d_ws;
    unsigned short* h_bf  = (unsigned short*)p;  p += (size_t)GN * DD * 2;   // atom output (layer 0)
    unsigned short* z2_bf = (unsigned short*)p;  p += (size_t)GN * DD * 2;   // raw z2 (layers 0-3)
    float* A              = (float*)p;           p += (size_t)GN * DD * 4;   // edge output
    float* z1             = (float*)p;           p += (size_t)GN * DD * 4;
    float* z2f            = (float*)p;           p += (size_t)GN * DD * 4;   // f32 z2 (layer 4)
    unsigned short* tbl_bl   = (unsigned short*)p;  p += (size_t)5 * (TQ + 1) * DD * 2;
    unsigned short* tbl_pr   = (unsigned short*)p;  p += (size_t)5 * (TQ + 1) * DD * 2;
    unsigned short* tbl_bond = (unsigned short*)p;  p += (size_t)5 * NBOND * DD * 2;
    unsigned short* wf_hi    = (unsigned short*)p;  p += (size_t)10 * 16384 * 2;
    unsigned short* wf_lo    = (unsigned short*)p;  p += (size_t)10 * 16384 * 2;
    float* stats_all = (float*)p;  p += (size_t)10 * SSET * 4;   // [layer][{1,2}][bank][256]
    int* count    = (int*)p;    p += (size_t)GN * 4;
    int* fill     = (int*)p;    p += (size_t)GN * 4;
    int* row_start= (int*)p;    p += (size_t)(GN + 1) * 4;
    int* blocksum = (int*)p;    p += (size_t)SCB * 4;
    int* blockoff = (int*)p;    p += (size_t)SCB * 4;
    p = (char*)(((size_t)p + 15) & ~(size_t)15);
    int4* ep      = (int4*)p;   p += (size_t)GE * 16;

    hipMemsetAsync(count, 0, (size_t)GN * 4, stream);
    hipMemsetAsync(fill,  0, (size_t)GN * 4, stream);
    hipMemsetAsync(stats_all, 0, (size_t)10 * SSET * 4, stream);

    hist_kernel<<<(GE + 255) / 256, 256, 0, stream>>>(ei, count);
    scan1_kernel<<<SCB, 1024, 0, stream>>>(count, row_start, blocksum);
    scan2_kernel<<<1, 64, 0, stream>>>(blocksum, blockoff);
    scan3_kernel<<<SCB, 1024, 0, stream>>>(row_start, blockoff);
    scatter_kernel<<<(GE + 255) / 256, 256, 0, stream>>>(ei, eai, eaf, row_start, fill, ep);
    atom_kernel<<<(GN * DD + 255) / 256, 256, 0, stream>>>(x, atom_off, atom_emb, h_bf);
    wfrag_kernel<<<80, 256, 0, stream>>>(W1, W2, wf_hi, wf_lo);
    tables_kernel<<<5 * TROWS, 128, 0, stream>>>(
        W_bl, b_bl, W_pr, b_pr, bond_emb, bond_off, tbl_bl, tbl_pr, tbl_bond);

    for (int l = 0; l < 5; l++) {
        float* stats1 = stats_all + (size_t)(2 * l + 0) * SSET;
        float* stats2 = stats_all + (size_t)(2 * l + 1) * SSET;
        float* stats2_prev = stats_all + (size_t)(2 * (l - 1) + 1) * SSET;

        // layer 0: hsrc = atom h (identity); layers 1-4: hsrc = raw z2 of l-1, bn2+relu on the fly
        if (l == 0) {
            edge_kernel<0><<<GN / 4, 256, 0, stream>>>(
                ep, tbl_bl, tbl_pr, tbl_bond,
                h_bf, row_start, eps_gin, l,
                stats_all, bng, bnb, A);
        } else {
            edge_kernel<1><<<GN / 4, 256, 0, stream>>>(
                ep,
                tbl_bl + (size_t)l * (TQ + 1) * DD,
                tbl_pr + (size_t)l * (TQ + 1) * DD,
                tbl_bond + (size_t)l * NBOND * DD,
                z2_bf, row_start, eps_gin, l,
                stats2_prev,
                bng + (size_t)(l - 1) * DD,
                bnb + (size_t)(l - 1) * DD,
                A);
        }

        gemm_kernel<0><<<NB, 256, 0, stream>>>(
            A, wf_hi + (size_t)(l * 2 + 0) * 16384, wf_lo + (size_t)(l * 2 + 0) * 16384,
            b1 + (size_t)l * DD, nullptr, z1, 0,
            nullptr, nullptr, nullptr, stats1);

        gemm_kernel<1><<<NB, 256, 0, stream>>>(
            z1, wf_hi + (size_t)(l * 2 + 1) * 16384, wf_lo + (size_t)(l * 2 + 1) * 16384,
            b2 + (size_t)l * DD, z2_bf, z2f, (l < 4) ? 1 : 0,
            stats1, bn1g + (size_t)l * DD, bn1b + (size_t)l * DD, stats2);
    }

    bn_apply_kernel<<<1024, 256, 0, stream>>>(
        z2f, stats_all + (size_t)9 * SSET, bng + (size_t)4 * DD, bnb + (size_t)4 * DD, out);
}